// Round 4
// baseline (24.206 us; speedup 1.0000x reference)
//
#include <hip/hip_runtime.h>

namespace {
constexpr int Bn = 64;
constexpr int Ln = 512;
constexpr int Hn = 768;
constexpr int Dn = 16;
constexpr int Qn = 32;      // max query rows; also softmax width
constexpr int SMAX = 28;    // seq_lens in [4,28] (or 0)
constexpr float NEGV = -900000.0f;
}

// ---------------------------------------------------------------------------
// One fused kernel. blocks [0,Bn): query pooling; blocks [Bn,Bn+Bn*Dn): doc.
// Phase 1: wave-per-row score (float4 dot over H=768 = 64 lanes x 12 cols,
//          single wave shfl-reduce, lane0 -> score_sh[s]).
// Softmax: 32 lanes of wave 0, masked; alpha written back to score_sh
//          (alpha = 0 for masked rows).
// Phase 2: branch-free pool — thread t owns cols {t,t+256,t+512}; loads ALL
//          SMAX/Qn rows unconditionally (alpha=0 kills masked rows exactly;
//          addresses provably < L). Full unroll -> ~84 loads in flight.
// Prefix offsets: lanes 0..15 hold slens[b,:]; shfl-sum (no serial chain).
// ---------------------------------------------------------------------------
__global__ __launch_bounds__(256) void k_fused(
    const float* __restrict__ hs,
    const float* __restrict__ Wd, const float* __restrict__ bd,
    const float* __restrict__ Wq, const float* __restrict__ bq,
    const int* __restrict__ qlen, const int* __restrict__ slens,
    float* __restrict__ out_doc, float* __restrict__ out_q)
{
    __shared__ float score_sh[Qn];          // raw scores, then alpha

    const int t = threadIdx.x;
    const int wave = t >> 6;
    const int lane = t & 63;
    const int bid = blockIdx.x;

    if (bid < Bn) {
        // ------------------------- query block -------------------------
        const int b = bid;
        const int ql = qlen[b];                          // 8..32, uniform
        const float* bp = hs + ((size_t)b * Ln + 1) * Hn;

        // phase 1: wave-per-row dot
        for (int s = wave; s < ql; s += 4) {
            const float* r = bp + s * Hn;
            float p = 0.f;
#pragma unroll
            for (int j = 0; j < 3; ++j) {
                const int e = (lane + 64 * j) * 4;
                const float4 v = *reinterpret_cast<const float4*>(r + e);
                const float4 w = *reinterpret_cast<const float4*>(Wq + e);
                p += v.x * w.x + v.y * w.y + v.z * w.z + v.w * w.w;
            }
#pragma unroll
            for (int off = 32; off; off >>= 1) p += __shfl_down(p, off);
            if (lane == 0) score_sh[s] = p;
        }
        __syncthreads();

        // softmax over Q=32, masked
        if (t < Qn) {
            const float raw = (t < ql) ? (score_sh[t] + bq[0]) : NEGV;
            float m = raw;
#pragma unroll
            for (int off = 16; off; off >>= 1) m = fmaxf(m, __shfl_xor(m, off, 32));
            const float e = expf(raw - m);
            float den = e;
#pragma unroll
            for (int off = 16; off; off >>= 1) den += __shfl_xor(den, off, 32);
            score_sh[t] = (t < ql) ? (e / den) : 0.f;
        }
        __syncthreads();

        // phase 2: branch-free pool over all 32 rows (alpha=0 for s>=ql)
        float a0 = 0.f, a1 = 0.f, a2 = 0.f;
#pragma unroll
        for (int s = 0; s < Qn; ++s) {
            const float a = score_sh[s];
            const float* row = bp + s * Hn;
            a0 += a * row[t];
            a1 += a * row[t + 256];
            a2 += a * row[t + 512];
        }
        for (int dd = 0; dd < Dn; ++dd) {
            float* o = out_q + ((size_t)b * Dn + dd) * Hn;
            o[t] = a0; o[t + 256] = a1; o[t + 512] = a2;
        }
    } else {
        // -------------------------- doc block --------------------------
        const int id = bid - Bn;
        const int b = id >> 4;
        const int d = id & 15;

        // parallel prefix: lane j (j<16) holds slens[b,j]; sum over j<d
        const int sv = slens[b * Dn + (lane & 15)];
        const int sl = __shfl(sv, d, 64);                // this doc's len
        float* o = out_doc + ((size_t)b * Dn + d) * Hn;
        if (sl == 0) {                                   // ~36% of doc blocks
            o[t] = 0.f; o[t + 256] = 0.f; o[t + 512] = 0.f;
            return;
        }
        int pref = 0;
#pragma unroll
        for (int k = 0; k < Dn; ++k)
            pref += (k < d) ? __shfl(sv, k, 64) : 0;
        const int base = qlen[b] + 2 + pref;             // max 454; +27 < 512
        const float* bp = hs + ((size_t)b * Ln + base) * Hn;

        // phase 1: wave-per-row dot over valid rows
        for (int s = wave; s < sl; s += 4) {
            const float* r = bp + s * Hn;
            float p = 0.f;
#pragma unroll
            for (int j = 0; j < 3; ++j) {
                const int e = (lane + 64 * j) * 4;
                const float4 v = *reinterpret_cast<const float4*>(r + e);
                const float4 w = *reinterpret_cast<const float4*>(Wd + e);
                p += v.x * w.x + v.y * w.y + v.z * w.z + v.w * w.w;
            }
#pragma unroll
            for (int off = 32; off; off >>= 1) p += __shfl_down(p, off);
            if (lane == 0) score_sh[s] = p;
        }
        __syncthreads();

        // softmax over 32 lanes (covers SMAX=28), masked
        if (t < Qn) {
            const float raw = (t < sl) ? (score_sh[t] + bd[0]) : NEGV;
            float m = raw;
#pragma unroll
            for (int off = 16; off; off >>= 1) m = fmaxf(m, __shfl_xor(m, off, 32));
            const float e = expf(raw - m);
            float den = e;
#pragma unroll
            for (int off = 16; off; off >>= 1) den += __shfl_xor(den, off, 32);
            score_sh[t] = (t < sl) ? (e / den) : 0.f;
        }
        __syncthreads();

        // phase 2: branch-free pool over all 28 candidate rows
        float a0 = 0.f, a1 = 0.f, a2 = 0.f;
#pragma unroll
        for (int s = 0; s < SMAX; ++s) {
            const float a = score_sh[s];
            const float* row = bp + s * Hn;
            a0 += a * row[t];
            a1 += a * row[t + 256];
            a2 += a * row[t + 512];
        }
        o[t] = a0; o[t + 256] = a1; o[t + 512] = a2;
    }
}

extern "C" void kernel_launch(void* const* d_in, const int* in_sizes, int n_in,
                              void* d_out, int out_size, void* d_ws, size_t ws_size,
                              hipStream_t stream)
{
    const float* hs    = (const float*)d_in[0];   // (B,L,H) f32
    const float* Wd    = (const float*)d_in[1];   // (H,1)
    const float* bd    = (const float*)d_in[2];   // (1,)
    const float* Wq    = (const float*)d_in[3];   // (H,1)
    const float* bq    = (const float*)d_in[4];   // (1,)
    const int*   qlen  = (const int*)d_in[5];     // (B,)
    const int*   slens = (const int*)d_in[6];     // (B,D)

    float* out_doc = (float*)d_out;                       // (B,D,H) doc_pooled
    float* out_q   = out_doc + (size_t)Bn * Dn * Hn;      // (B,D,H) q_bcast

    k_fused<<<Bn + Bn * Dn, 256, 0, stream>>>(hs, Wd, bd, Wq, bq,
                                              qlen, slens, out_doc, out_q);
}

// Round 5
// 16.360 us; speedup vs baseline: 1.4796x; 1.4796x over previous
//
#include <hip/hip_runtime.h>

namespace {
constexpr int Bn = 64;
constexpr int Ln = 512;
constexpr int Hn = 768;
constexpr int Dn = 16;
constexpr int Qn = 32;      // max query rows; softmax width
constexpr float NEGV = -900000.0f;
}

// ---------------------------------------------------------------------------
// Single-read fused kernel. blocks [0,Bn): query; [Bn,Bn+Bn*Dn): doc.
// Wave w owns rows {w, w+4, w+8, ...}. Phase 1 loads each row ONCE as
// 3 float4/lane (lane+64j layout covers all 768 cols in one wave), computes
// the score via one wave shfl-reduce, and KEEPS the row in registers.
// Softmax in 32 lanes. Phase 2 is pure register FMA into a per-wave float4
// accumulator; the 4 wave partials combine through a 12 KB LDS buffer.
// Every hidden_states byte is read exactly once, as dwordx4.
// ---------------------------------------------------------------------------
template<int NIT>
__device__ __forceinline__ void pool_span(
    const float* __restrict__ rowbase,   // &hs[(b*L + first_row) * H]
    const float* __restrict__ W, float bias, int len,
    float* __restrict__ score_sh, float (*pool_sh)[Hn],
    int t, int wave, int lane, float out3[3])
{
    float4 wv[3];
#pragma unroll
    for (int j = 0; j < 3; ++j)
        wv[j] = *reinterpret_cast<const float4*>(W + (lane + 64 * j) * 4);

    // phase 1: load rows once, score, keep in registers
    float4 c[NIT][3];
#pragma unroll
    for (int it = 0; it < NIT; ++it) {
        const int s = wave + 4 * it;              // wave-uniform predicate
        if (s < len) {
            const float* r = rowbase + s * Hn;
#pragma unroll
            for (int j = 0; j < 3; ++j)
                c[it][j] = *reinterpret_cast<const float4*>(r + (lane + 64 * j) * 4);
            float p = c[it][0].x * wv[0].x + c[it][0].y * wv[0].y
                    + c[it][0].z * wv[0].z + c[it][0].w * wv[0].w
                    + c[it][1].x * wv[1].x + c[it][1].y * wv[1].y
                    + c[it][1].z * wv[1].z + c[it][1].w * wv[1].w
                    + c[it][2].x * wv[2].x + c[it][2].y * wv[2].y
                    + c[it][2].z * wv[2].z + c[it][2].w * wv[2].w;
#pragma unroll
            for (int off = 32; off; off >>= 1) p += __shfl_down(p, off);
            if (lane == 0) score_sh[s] = p;
        }
    }
    __syncthreads();

    // masked softmax in 32 lanes; alpha (0 for masked) back to score_sh
    if (t < Qn) {
        const float raw = (t < len) ? (score_sh[t] + bias) : NEGV;
        float m = raw;
#pragma unroll
        for (int off = 16; off; off >>= 1) m = fmaxf(m, __shfl_xor(m, off, 32));
        const float e = expf(raw - m);
        float den = e;
#pragma unroll
        for (int off = 16; off; off >>= 1) den += __shfl_xor(den, off, 32);
        score_sh[t] = (t < len) ? (e / den) : 0.f;
    }
    __syncthreads();

    // phase 2: pure register FMA per wave
    float4 acc[3];
#pragma unroll
    for (int j = 0; j < 3; ++j) acc[j] = make_float4(0.f, 0.f, 0.f, 0.f);
#pragma unroll
    for (int it = 0; it < NIT; ++it) {
        const int s = wave + 4 * it;
        if (s < len) {
            const float a = score_sh[s];          // LDS broadcast
#pragma unroll
            for (int j = 0; j < 3; ++j) {
                acc[j].x += a * c[it][j].x;
                acc[j].y += a * c[it][j].y;
                acc[j].z += a * c[it][j].z;
                acc[j].w += a * c[it][j].w;
            }
        }
    }

    // cross-wave combine through LDS
#pragma unroll
    for (int j = 0; j < 3; ++j)
        *reinterpret_cast<float4*>(&pool_sh[wave][(lane + 64 * j) * 4]) = acc[j];
    __syncthreads();
    out3[0] = pool_sh[0][t]       + pool_sh[1][t]       + pool_sh[2][t]       + pool_sh[3][t];
    out3[1] = pool_sh[0][t + 256] + pool_sh[1][t + 256] + pool_sh[2][t + 256] + pool_sh[3][t + 256];
    out3[2] = pool_sh[0][t + 512] + pool_sh[1][t + 512] + pool_sh[2][t + 512] + pool_sh[3][t + 512];
}

__global__ __launch_bounds__(256) void k_fused(
    const float* __restrict__ hs,
    const float* __restrict__ Wd, const float* __restrict__ bd,
    const float* __restrict__ Wq, const float* __restrict__ bq,
    const int* __restrict__ qlen, const int* __restrict__ slens,
    float* __restrict__ out_doc, float* __restrict__ out_q)
{
    __shared__ float score_sh[Qn];
    __shared__ float pool_sh[4][Hn];

    const int t = threadIdx.x;
    const int wave = t >> 6;
    const int lane = t & 63;
    const int bid = blockIdx.x;

    if (bid < Bn) {
        // ------------------------- query block -------------------------
        const int b = bid;
        const int ql = qlen[b];                            // 8..32
        const float* bp = hs + ((size_t)b * Ln + 1) * Hn;
        float o3[3];
        pool_span<8>(bp, Wq, bq[0], ql, score_sh, pool_sh, t, wave, lane, o3);
        for (int dd = 0; dd < Dn; ++dd) {
            float* o = out_q + ((size_t)b * Dn + dd) * Hn;
            o[t] = o3[0]; o[t + 256] = o3[1]; o[t + 512] = o3[2];
        }
    } else {
        // -------------------------- doc block --------------------------
        const int id = bid - Bn;
        const int b = id >> 4;
        const int d = id & 15;

        const int sv = slens[b * Dn + (lane & 15)];        // parallel prefix
        const int sl = __shfl(sv, d, 64);                  // this doc's len
        float* o = out_doc + ((size_t)b * Dn + d) * Hn;
        if (sl == 0) {                                     // ~36% of doc blocks
            o[t] = 0.f; o[t + 256] = 0.f; o[t + 512] = 0.f;
            return;
        }
        int pref = 0;
#pragma unroll
        for (int k = 0; k < Dn; ++k)
            pref += (k < d) ? __shfl(sv, k, 64) : 0;
        const int base = qlen[b] + 2 + pref;               // +27 max = 481 < 512
        const float* bp = hs + ((size_t)b * Ln + base) * Hn;
        float o3[3];
        pool_span<7>(bp, Wd, bd[0], sl, score_sh, pool_sh, t, wave, lane, o3);
        o[t] = o3[0]; o[t + 256] = o3[1]; o[t + 512] = o3[2];
    }
}

extern "C" void kernel_launch(void* const* d_in, const int* in_sizes, int n_in,
                              void* d_out, int out_size, void* d_ws, size_t ws_size,
                              hipStream_t stream)
{
    const float* hs    = (const float*)d_in[0];   // (B,L,H) f32
    const float* Wd    = (const float*)d_in[1];   // (H,1)
    const float* bd    = (const float*)d_in[2];   // (1,)
    const float* Wq    = (const float*)d_in[3];   // (H,1)
    const float* bq    = (const float*)d_in[4];   // (1,)
    const int*   qlen  = (const int*)d_in[5];     // (B,)
    const int*   slens = (const int*)d_in[6];     // (B,D)

    float* out_doc = (float*)d_out;                       // (B,D,H) doc_pooled
    float* out_q   = out_doc + (size_t)Bn * Dn * Hn;      // (B,D,H) q_bcast

    k_fused<<<Bn + Bn * Dn, 256, 0, stream>>>(hs, Wd, bd, Wq, bq,
                                              qlen, slens, out_doc, out_q);
}